// Round 1
// baseline (284.179 us; speedup 1.0000x reference)
//
#include <hip/hip_runtime.h>
#include <math.h>

// Problem constants (from reference)
constexpr int Bn   = 32;
constexpr int L    = 65536;          // T*K
constexpr int NCH  = 6;
constexpr int SEG  = 128;            // elements per thread-segment
constexpr int NSEG = L / SEG;        // 512 segments per chain
constexpr int ROW  = L * NCH;        // 393216 floats per batch row (imu/mn/out)
constexpr int EPW_ROW = (L - 1) * NCH; // 393210 floats per batch row (eps_walk)
constexpr int NPART = Bn * NSEG * NCH; // 98304 partials / carries

// x^(2^k) in double
__device__ __forceinline__ double pow2k(double x, int k) {
    for (int i = 0; i < k; ++i) x *= x;
    return x;
}

// ---------------- Kernel 1: per-segment weighted partial sums ----------------
// partial[s] = sum_{j in seg} a^(segend-j) * x[j],  x[0]=eps0*std0, x[j>=1]=ds*eps_walk[j-1]
__global__ __launch_bounds__(256) void k_partials(
    const float* __restrict__ eps0,
    const float* __restrict__ epw,
    float* __restrict__ part)
{
    int tid = blockIdx.x * 256 + threadIdx.x;   // 0..NPART-1
    int c  = tid % NCH;
    int rs = tid / NCH;          // b*NSEG + s
    int s  = rs % NSEG;
    int b  = rs / NSEG;

    const float af  = (float)(1.0 - 0.01 * 0.001);      // a = 0.99999 (fp32)
    const float std0 = (c < 3) ? 0.2f : 0.015f;
    const float ds   = std0 * 0.004472135954999579f;     // std0*sqrt(2*theta)*sqrt(dt)

    int l0 = s * SEG;
    const float* ep = epw + (size_t)b * EPW_ROW + ((size_t)l0 - 1) * NCH + c;

    float p = 0.f;
    if (l0 == 0) {
        // j = 0: x = bias0 (no eps_walk read — would be out of bounds)
        p = eps0[b * NCH + c] * std0;
        #pragma unroll 4
        for (int j = 1; j < SEG; ++j)
            p = fmaf(af, p, ds * ep[j * NCH]);
    } else {
        #pragma unroll 4
        for (int j = 0; j < SEG; ++j)
            p = fmaf(af, p, ds * ep[j * NCH]);
    }
    part[tid] = p;
}

// ---------------- Kernel 2: per-chain scan of segment partials ----------------
// One wave (64 lanes) per chain; lane owns 8 consecutive segments.
// E_s = A * E_{s-1} + P_s with A = a^SEG. Writes carry[s] = E_{s-1}.
__global__ __launch_bounds__(64) void k_scan(
    const float* __restrict__ part,
    float* __restrict__ carry)
{
    int lane  = threadIdx.x;         // 0..63
    int chain = blockIdx.x;          // 0..191
    int b = chain / NCH, c = chain % NCH;
    int base = b * (NSEG * NCH) + c;

    const double a  = (double)((float)(1.0 - 0.01 * 0.001));
    const double A  = pow2k(a, 7);   // a^128
    const double A8 = pow2k(A, 3);   // a^1024 (per-lane span)

    int s0 = lane * 8;
    float pv[8];
    #pragma unroll
    for (int k = 0; k < 8; ++k)
        pv[k] = part[base + (s0 + k) * NCH];

    // lane total T = scan of 8 partials with coefficient A, zero init
    double t = 0.0;
    #pragma unroll
    for (int k = 0; k < 8; ++k) t = A * t + (double)pv[k];

    // Kogge-Stone inclusive scan across lanes: I_lane = sum_{u<=lane} A8^(lane-u) T_u
    double I = t;
    double m = A8;
    #pragma unroll
    for (int d = 1; d <= 32; d <<= 1) {
        double up = __shfl_up(I, d, 64);
        if (lane >= d) I = m * up + I;
        m = m * m;
    }
    double cin = __shfl_up(I, 1, 64);   // E at end of previous lane's last segment
    if (lane == 0) cin = 0.0;

    double e = cin;
    #pragma unroll
    for (int k = 0; k < 8; ++k) {
        carry[base + (s0 + k) * NCH] = (float)e;  // E_{s-1}
        e = A * e + (double)pv[k];
    }
}

// ---------------- Kernel 3: replay segments with carry + fused elementwise ----
__global__ __launch_bounds__(256) void k_apply(
    const float* __restrict__ imu,
    const float* __restrict__ eps0,
    const float* __restrict__ epw,
    const float* __restrict__ mn,
    const float* __restrict__ carry,
    float* __restrict__ out)
{
    int tid = blockIdx.x * 256 + threadIdx.x;
    int c  = tid % NCH;
    int rs = tid / NCH;
    int s  = rs % NSEG;
    int b  = rs / NSEG;

    const float af   = (float)(1.0 - 0.01 * 0.001);
    const float std0 = (c < 3) ? 0.2f : 0.015f;
    const float ds   = std0 * 0.004472135954999579f;
    const float nstd = (c < 3) ? 0.1f  : 0.01f;
    const float tcf  = (c < 3) ? 0.001f : 0.01f;   // 0.1*TEMP_COEF / TEMP_COEF

    int l0 = s * SEG;
    size_t rowoff = (size_t)b * ROW + (size_t)l0 * NCH + c;
    const float* ip = imu + rowoff;
    const float* mp = mn  + rowoff;
    float*       op = out + rowoff;
    const float* ep = epw + (size_t)b * EPW_ROW + ((size_t)l0 - 1) * NCH + c;

    const float inv   = 1.0f / 65535.0f;
    const float twopi = 6.283185307179586f;

    float e = carry[tid];

    // peel j = 0 (guards the l==0 eps0 seed; no OOB eps_walk read)
    {
        float x;
        if (l0 == 0) x = eps0[b * NCH + c] * std0;
        else         x = ds * ep[0];
        e = fmaf(af, e, x);
        float tt = (float)l0 * inv;
        float temp = fmaf(5.0f, sinf(twopi * tt), fmaf(2.0f, tt, 20.0f));
        op[0] = ip[0] + e + mp[0] * nstd + temp * tcf;
    }
    #pragma unroll 4
    for (int j = 1; j < SEG; ++j) {
        e = fmaf(af, e, ds * ep[j * NCH]);
        float tt = (float)(l0 + j) * inv;
        float temp = fmaf(5.0f, sinf(twopi * tt), fmaf(2.0f, tt, 20.0f));
        op[j * NCH] = ip[j * NCH] + e + mp[j * NCH] * nstd + temp * tcf;
    }
}

extern "C" void kernel_launch(void* const* d_in, const int* in_sizes, int n_in,
                              void* d_out, int out_size, void* d_ws, size_t ws_size,
                              hipStream_t stream) {
    const float* imu  = (const float*)d_in[0];   // [B, T, K, 6] = [B, L, 6]
    const float* eps0 = (const float*)d_in[1];   // [B, 6]
    const float* epw  = (const float*)d_in[2];   // [B, L-1, 6]
    const float* mn   = (const float*)d_in[3];   // [B, L, 6]
    float* out = (float*)d_out;

    float* part  = (float*)d_ws;          // NPART floats
    float* carry = part + NPART;          // NPART floats

    k_partials<<<NPART / 256, 256, 0, stream>>>(eps0, epw, part);
    k_scan<<<Bn * NCH, 64, 0, stream>>>(part, carry);
    k_apply<<<NPART / 256, 256, 0, stream>>>(imu, eps0, epw, mn, carry, out);
}

// Round 2
// 217.042 us; speedup vs baseline: 1.3093x; 1.3093x over previous
//
#include <hip/hip_runtime.h>
#include <math.h>

// Problem constants (from reference)
constexpr int Bn   = 32;
constexpr int L    = 65536;            // T*K
constexpr int NCH  = 6;
constexpr int SEG  = 32;               // elements per thread-segment (was 128)
constexpr int NSEG = L / SEG;          // 2048 segments per chain
constexpr int ROW  = L * NCH;          // floats per batch row (imu/mn/out)
constexpr int EPW_ROW = (L - 1) * NCH; // floats per batch row (eps_walk)
constexpr int NPART = Bn * NSEG * NCH; // 393216 partials / carries
constexpr int SEG_PER_LANE = NSEG / 64; // 32 segments per lane in k_scan

// x^(2^k) in double
__device__ __forceinline__ double pow2k(double x, int k) {
    for (int i = 0; i < k; ++i) x *= x;
    return x;
}

// ---------------- Kernel 1: per-segment weighted partial sums ----------------
// partial[s] = sum_{j in seg} a^(segend-j) * x[j],  x[0]=eps0*std0, x[j>=1]=ds*eps_walk[j-1]
__global__ __launch_bounds__(256) void k_partials(
    const float* __restrict__ eps0,
    const float* __restrict__ epw,
    float* __restrict__ part)
{
    int tid = blockIdx.x * 256 + threadIdx.x;   // 0..NPART-1
    int c  = tid % NCH;
    int rs = tid / NCH;          // b*NSEG + s
    int s  = rs % NSEG;
    int b  = rs / NSEG;

    const float af   = 0.99999f;                        // a = 1 - theta*dt
    const float std0 = (c < 3) ? 0.2f : 0.015f;
    const float ds   = std0 * 0.004472135954999579f;    // std0*sqrt(2*theta*dt)

    int l0 = s * SEG;
    const float* ep = epw + (size_t)b * EPW_ROW + ((size_t)l0 - 1) * NCH + c;

    float p = 0.f;
    if (l0 == 0) {
        p = eps0[b * NCH + c] * std0;   // j=0: bias0 seed, no eps_walk read
        #pragma unroll
        for (int j = 1; j < SEG; ++j)
            p = fmaf(af, p, ds * ep[j * NCH]);
    } else {
        #pragma unroll
        for (int j = 0; j < SEG; ++j)
            p = fmaf(af, p, ds * ep[j * NCH]);
    }
    part[tid] = p;
}

// ---------------- Kernel 2: per-chain scan of segment partials ----------------
// One wave per chain; lane owns SEG_PER_LANE consecutive segments.
// E_s = A * E_{s-1} + P_s with A = a^SEG. Writes carry[s] = E_{s-1}.
__global__ __launch_bounds__(64) void k_scan(
    const float* __restrict__ part,
    float* __restrict__ carry)
{
    int lane  = threadIdx.x;         // 0..63
    int chain = blockIdx.x;          // 0..191
    int b = chain / NCH, c = chain % NCH;
    int base = b * (NSEG * NCH) + c;

    const double a    = (double)0.99999f;
    const double A    = pow2k(a, 5);              // a^32 (per-segment)
    const double Alan = pow2k(A, 5);              // A^32 (per-lane span)

    int s0 = lane * SEG_PER_LANE;
    float pv[SEG_PER_LANE];
    #pragma unroll
    for (int k = 0; k < SEG_PER_LANE; ++k)
        pv[k] = part[base + (s0 + k) * NCH];

    // lane total = scan of SEG_PER_LANE partials with coefficient A, zero init
    double t = 0.0;
    #pragma unroll
    for (int k = 0; k < SEG_PER_LANE; ++k) t = A * t + (double)pv[k];

    // Kogge-Stone inclusive scan across lanes
    double I = t;
    double m = Alan;
    #pragma unroll
    for (int d = 1; d <= 32; d <<= 1) {
        double up = __shfl_up(I, d, 64);
        if (lane >= d) I = m * up + I;
        m = m * m;
    }
    double cin = __shfl_up(I, 1, 64);   // E at end of previous lane's last segment
    if (lane == 0) cin = 0.0;

    double e = cin;
    #pragma unroll
    for (int k = 0; k < SEG_PER_LANE; ++k) {
        carry[base + (s0 + k) * NCH] = (float)e;  // E_{s-1}
        e = A * e + (double)pv[k];
    }
}

// ---------------- Kernel 3: replay segments with carry + fused elementwise ----
__global__ __launch_bounds__(256) void k_apply(
    const float* __restrict__ imu,
    const float* __restrict__ eps0,
    const float* __restrict__ epw,
    const float* __restrict__ mn,
    const float* __restrict__ carry,
    float* __restrict__ out)
{
    int tid = blockIdx.x * 256 + threadIdx.x;
    int c  = tid % NCH;
    int rs = tid / NCH;
    int s  = rs % NSEG;
    int b  = rs / NSEG;

    const float af   = 0.99999f;
    const float std0 = (c < 3) ? 0.2f : 0.015f;
    const float ds   = std0 * 0.004472135954999579f;
    const float nstd = (c < 3) ? 0.1f  : 0.01f;
    const float tcf  = (c < 3) ? 0.001f : 0.01f;   // 0.1*TEMP_COEF / TEMP_COEF

    int l0 = s * SEG;
    size_t rowoff = (size_t)b * ROW + (size_t)l0 * NCH + c;
    const float* ip = imu + rowoff;
    const float* mp = mn  + rowoff;
    float*       op = out + rowoff;
    const float* ep = epw + (size_t)b * EPW_ROW + ((size_t)l0 - 1) * NCH + c;

    const float inv   = 1.0f / 65535.0f;
    const float twopi = 6.283185307179586f;

    float e = carry[tid];

    // peel j = 0 (guards the l==0 eps0 seed; no OOB eps_walk read)
    {
        float x;
        if (l0 == 0) x = eps0[b * NCH + c] * std0;
        else         x = ds * ep[0];
        e = fmaf(af, e, x);
        float tt = (float)l0 * inv;
        float temp = fmaf(5.0f, __sinf(twopi * tt), fmaf(2.0f, tt, 20.0f));
        op[0] = ip[0] + e + mp[0] * nstd + temp * tcf;
    }
    #pragma unroll
    for (int j = 1; j < SEG; ++j) {
        e = fmaf(af, e, ds * ep[j * NCH]);
        float tt = (float)(l0 + j) * inv;
        float temp = fmaf(5.0f, __sinf(twopi * tt), fmaf(2.0f, tt, 20.0f));
        op[j * NCH] = ip[j * NCH] + e + mp[j * NCH] * nstd + temp * tcf;
    }
}

extern "C" void kernel_launch(void* const* d_in, const int* in_sizes, int n_in,
                              void* d_out, int out_size, void* d_ws, size_t ws_size,
                              hipStream_t stream) {
    const float* imu  = (const float*)d_in[0];   // [B, L, 6]
    const float* eps0 = (const float*)d_in[1];   // [B, 6]
    const float* epw  = (const float*)d_in[2];   // [B, L-1, 6]
    const float* mn   = (const float*)d_in[3];   // [B, L, 6]
    float* out = (float*)d_out;

    float* part  = (float*)d_ws;          // NPART floats
    float* carry = part + NPART;          // NPART floats

    k_partials<<<NPART / 256, 256, 0, stream>>>(eps0, epw, part);
    k_scan<<<Bn * NCH, 64, 0, stream>>>(part, carry);
    k_apply<<<NPART / 256, 256, 0, stream>>>(imu, eps0, epw, mn, carry, out);
}

// Round 3
// 192.733 us; speedup vs baseline: 1.4745x; 1.1261x over previous
//
#include <hip/hip_runtime.h>
#include <math.h>

// Problem constants
constexpr int Bn   = 32;
constexpr int L    = 65536;            // T*K
constexpr int NCH  = 6;
constexpr int SPAN = 256;              // hexads (l-steps) per wave-span
constexpr int NS   = L / SPAN;         // 256 spans per batch row
constexpr int ROW  = L * NCH;          // floats per row (imu/mn/out)
constexpr int EPW_ROW = (L - 1) * NCH; // floats per row (eps_walk)
constexpr int NWAVE = Bn * NS;         // 8192 wave-spans
constexpr float AF = 0.99999f;         // a = 1 - theta*dt (fp32, matches ref)
constexpr float DS_ACC  = 0.2f   * 0.004472135954999579f; // std*sqrt(2*theta*dt)
constexpr float DS_GYRO = 0.015f * 0.004472135954999579f;

// a^(lane+1) and a^(63-lane), double-accurate, computed once per thread
__device__ __forceinline__ void lane_pows(int lane, float& ap1, float& arev) {
    const double a = (double)AF;
    double t = a, p1 = 1.0, pr = 1.0;
    int e1 = lane + 1, er = 63 - lane;
    #pragma unroll
    for (int k = 0; k < 7; ++k) {
        if (e1 & (1 << k)) p1 *= t;
        if (er & (1 << k)) pr *= t;
        t *= t;
    }
    ap1 = (float)p1; arev = (float)pr;
}

// load one hexad of scaled innovation x[6] for step l (handles l==0 seed)
__device__ __forceinline__ void load_x(const float* __restrict__ epw,
                                       const float* __restrict__ eps0,
                                       int b, int l, float x[6]) {
    int lm1 = (l == 0) ? 0 : l - 1;                 // clamp (safe addr)
    const float2* p = (const float2*)(epw + (size_t)b * EPW_ROW + (size_t)lm1 * NCH);
    float2 v0 = p[0], v1 = p[1], v2 = p[2];
    x[0] = v0.x * DS_ACC;  x[1] = v0.y * DS_ACC;  x[2] = v1.x * DS_ACC;
    x[3] = v1.y * DS_GYRO; x[4] = v2.x * DS_GYRO; x[5] = v2.y * DS_GYRO;
    if (l == 0) {                                   // bias0 seed = eps0*std0
        const float* e0 = eps0 + b * NCH;
        x[0] = e0[0] * 0.2f;   x[1] = e0[1] * 0.2f;   x[2] = e0[2] * 0.2f;
        x[3] = e0[3] * 0.015f; x[4] = e0[4] * 0.015f; x[5] = e0[5] * 0.015f;
    }
}

// ---------- K1: per-span weighted aggregates (coalesced epw read) ----------
__global__ __launch_bounds__(256) void k_partials(
    const float* __restrict__ eps0,
    const float* __restrict__ epw,
    float* __restrict__ part)
{
    int lane = threadIdx.x & 63;
    int w = blockIdx.x * 4 + (threadIdx.x >> 6);   // wave-span id
    int b = w / NS, s = w % NS;

    float ap1, arev; lane_pows(lane, ap1, arev);
    double a64d = (double)AF;
    #pragma unroll
    for (int k = 0; k < 6; ++k) a64d *= a64d;      // a^64
    const float A64 = (float)a64d;

    float e0c = 0.f, e1c = 0.f, e2c = 0.f, e3c = 0.f, e4c = 0.f, e5c = 0.f;
    int l0 = s * SPAN;
    #pragma unroll
    for (int it = 0; it < SPAN / 64; ++it) {
        int l = l0 + it * 64 + lane;
        float x[6]; load_x(epw, eps0, b, l, x);
        float z[6];
        #pragma unroll
        for (int c = 0; c < 6; ++c) {
            z[c] = arev * x[c];
            #pragma unroll
            for (int m = 1; m < 64; m <<= 1) z[c] += __shfl_xor(z[c], m, 64);
        }
        e0c = fmaf(A64, e0c, z[0]); e1c = fmaf(A64, e1c, z[1]);
        e2c = fmaf(A64, e2c, z[2]); e3c = fmaf(A64, e3c, z[3]);
        e4c = fmaf(A64, e4c, z[4]); e5c = fmaf(A64, e5c, z[5]);
    }
    if (lane < 6) {
        float v = e0c;
        if (lane == 1) v = e1c; else if (lane == 2) v = e2c;
        else if (lane == 3) v = e3c; else if (lane == 4) v = e4c;
        else if (lane == 5) v = e5c;
        part[(size_t)w * NCH + lane] = v;
    }
}

// ---------- K2: scan span aggregates per chain (tiny, double) ----------
__global__ __launch_bounds__(64) void k_scan(
    const float* __restrict__ part,
    float* __restrict__ carry)
{
    int lane = threadIdx.x;
    int chain = blockIdx.x;              // b*6 + c
    int b = chain / NCH, c = chain % NCH;

    double a = (double)AF;
    double A = a;
    #pragma unroll
    for (int k = 0; k < 8; ++k) A *= A;  // a^256 = a^SPAN
    double A4 = A * A; A4 *= A4;         // A^4 (per-lane span of 4 segments)

    int s0 = lane * 4;
    size_t base = (size_t)b * NS * NCH + c;
    float pv[4];
    #pragma unroll
    for (int k = 0; k < 4; ++k) pv[k] = part[base + (size_t)(s0 + k) * NCH];

    double t = 0.0;
    #pragma unroll
    for (int k = 0; k < 4; ++k) t = A * t + (double)pv[k];

    double I = t, m = A4;
    #pragma unroll
    for (int d = 1; d <= 32; d <<= 1) {
        double up = __shfl_up(I, d, 64);
        if (lane >= d) I = m * up + I;
        m = m * m;
    }
    double cin = __shfl_up(I, 1, 64);
    if (lane == 0) cin = 0.0;

    double e = cin;
    #pragma unroll
    for (int k = 0; k < 4; ++k) {
        carry[base + (size_t)(s0 + k) * NCH] = (float)e;  // E_{s-1}
        e = A * e + (double)pv[k];
    }
}

// ---------- K3: fused scan + elementwise, fully coalesced ----------
__global__ __launch_bounds__(256) void k_apply(
    const float* __restrict__ imu,
    const float* __restrict__ eps0,
    const float* __restrict__ epw,
    const float* __restrict__ mn,
    const float* __restrict__ carry,
    float* __restrict__ out)
{
    int lane = threadIdx.x & 63;
    int w = blockIdx.x * 4 + (threadIdx.x >> 6);
    int b = w / NS, s = w % NS;

    float ap1, arev; lane_pows(lane, ap1, arev);

    float e[6];
    #pragma unroll
    for (int c = 0; c < 6; ++c) e[c] = carry[(size_t)w * NCH + c];

    const float inv   = 1.0f / 65535.0f;
    const float twopi = 6.283185307179586f;
    int l0 = s * SPAN;

    #pragma unroll
    for (int it = 0; it < SPAN / 64; ++it) {
        int l = l0 + it * 64 + lane;
        float x[6]; load_x(epw, eps0, b, l, x);

        // per-channel weighted inclusive scan (Kogge-Stone) + carry apply
        float bias[6];
        #pragma unroll
        for (int c = 0; c < 6; ++c) {
            float S = x[c], m = AF;
            #pragma unroll
            for (int d = 1; d < 64; d <<= 1) {
                float up = __shfl_up(S, d, 64);
                if (lane >= d) S = fmaf(m, up, S);
                m *= m;
            }
            bias[c] = fmaf(ap1, e[c], S);
            e[c] = __shfl(bias[c], 63, 64);   // carry for next iteration
        }

        float tt = (float)l * inv;
        float temp = fmaf(5.0f, __sinf(twopi * tt), fmaf(2.0f, tt, 20.0f));
        float ta = temp * 0.001f, tg = temp * 0.01f;

        size_t roff = (size_t)b * ROW + (size_t)l * NCH;
        const float2* ip = (const float2*)(imu + roff);
        const float2* mp = (const float2*)(mn + roff);
        float2* op = (float2*)(out + roff);
        float2 i0 = ip[0], i1 = ip[1], i2 = ip[2];
        float2 m0 = mp[0], m1 = mp[1], m2 = mp[2];
        float2 o0, o1, o2;
        o0.x = i0.x + bias[0] + m0.x * 0.1f  + ta;
        o0.y = i0.y + bias[1] + m0.y * 0.1f  + ta;
        o1.x = i1.x + bias[2] + m1.x * 0.1f  + ta;
        o1.y = i1.y + bias[3] + m1.y * 0.01f + tg;
        o2.x = i2.x + bias[4] + m2.x * 0.01f + tg;
        o2.y = i2.y + bias[5] + m2.y * 0.01f + tg;
        op[0] = o0; op[1] = o1; op[2] = o2;
    }
}

extern "C" void kernel_launch(void* const* d_in, const int* in_sizes, int n_in,
                              void* d_out, int out_size, void* d_ws, size_t ws_size,
                              hipStream_t stream) {
    const float* imu  = (const float*)d_in[0];   // [B, L, 6]
    const float* eps0 = (const float*)d_in[1];   // [B, 6]
    const float* epw  = (const float*)d_in[2];   // [B, L-1, 6]
    const float* mn   = (const float*)d_in[3];   // [B, L, 6]
    float* out = (float*)d_out;

    float* part  = (float*)d_ws;                 // NWAVE*6 floats
    float* carry = part + (size_t)NWAVE * NCH;   // NWAVE*6 floats

    k_partials<<<NWAVE / 4, 256, 0, stream>>>(eps0, epw, part);
    k_scan<<<Bn * NCH, 64, 0, stream>>>(part, carry);
    k_apply<<<NWAVE / 4, 256, 0, stream>>>(imu, eps0, epw, mn, carry, out);
}